// Round 8
// baseline (141.557 us; speedup 1.0000x reference)
//
#include <hip/hip_runtime.h>

// Problem constants (match reference)
constexpr int T     = 4;
constexpr int NROWS = 1000000;
constexpr int B     = 16384;
constexpr int TOTAL = 16384 * 50; // 819200 lookups per table

// Native clang vector type — required by __builtin_nontemporal_load
typedef float fv4 __attribute__((ext_vector_type(4)));

// ws layout: p[T*NROWS] floats (16 MB, 4 MB per table slice).
//
// XCD-pinning contract (both kernels use the identical mapping):
//   xcd = blockIdx.x & 7 ; table t = xcd >> 1 ; so table t's p slice is
//   WRITTEN by and GATHERED by only XCDs {2t, 2t+1}. The 4 MB slice stays
//   dirty-resident in that XCD pair's L2 between the two kernels -> pool's
//   random gathers are local L2 hits with no first-touch refill.

constexpr int BLOCKS_PER_TABLE = 3908;  // even; 3907*256 >= NROWS

// Producer: p[t*NROWS + r] = dot(table[t][r], W), streaming nt table loads,
// regular p stores (retention in local L2 is the point).
// Fused out[:] = bias init (pool's atomics accumulate on top of bias).
__global__ __launch_bounds__(256)
void produce_kernel(const fv4*   __restrict__ tables,
                    const float* __restrict__ Wp,
                    const float* __restrict__ bias,
                    float* __restrict__ p,
                    float* __restrict__ out) {
    const int xcd    = blockIdx.x & 7;
    const int t      = xcd >> 1;
    const int within = (blockIdx.x >> 3) * 2 + (xcd & 1);   // [0, 3908)
    const int r      = within * 256 + threadIdx.x;

    if (r < NROWS) {
        const float wx = Wp[0], wy = Wp[1], wz = Wp[2], ww = Wp[3];
        const fv4 row = __builtin_nontemporal_load(&tables[t * NROWS + r]);
        p[t * NROWS + r] = row.x * wx + row.y * wy + row.z * wz + row.w * ww;
    }

    const int gid = blockIdx.x * 256 + threadIdx.x;
    if (gid < T * B) out[gid] = bias[0];
}

// Pool: one lookup per thread. Wave-level segmented inclusive scan over
// sorted segment ids (conditional Hillis-Steele — valid because equal segs
// are contiguous); only the last lane of each run flushes via atomicAdd
// (~102k atomics over 65k addresses => ~2/address, no serialization).
// idx/seg loads are non-temporal so the 26 MB stream doesn't evict the
// L2-resident p slice.
__global__ __launch_bounds__(256)
void pool_kernel(const float* __restrict__ p,        // [T*NROWS]
                 const int*   __restrict__ indices,  // [T*TOTAL]
                 const int*   __restrict__ segids,   // [T*TOTAL] sorted per table
                 float*       __restrict__ out)      // [T*B], pre-set to bias
{
    // 12800 blocks: 3200 per table (256 lookups each), same XCD mapping as produce.
    const int xcd    = blockIdx.x & 7;
    const int t      = xcd >> 1;
    const int within = (blockIdx.x >> 3) * 2 + (xcd & 1);   // [0, 3200)
    const int local  = within * 256 + threadIdx.x;
    const int g      = t * TOTAL + local;

    const int lane = threadIdx.x & 63;

    const int seg = __builtin_nontemporal_load(&segids[g]);
    const int idx = __builtin_nontemporal_load(&indices[g]);
    float v = p[t * NROWS + idx];

    // Segmented inclusive scan across the 64-lane wave.
    #pragma unroll
    for (int d = 1; d < 64; d <<= 1) {
        const float ov = __shfl_up(v, d, 64);
        const int   os = __shfl_up(seg, d, 64);
        if (lane >= d && os == seg) v += ov;
    }

    // Last lane of each same-seg run in this wave flushes the run sum.
    const int nseg = __shfl_down(seg, 1, 64);
    if (lane == 63 || nseg != seg) {
        atomicAdd(&out[t * B + seg], v);
    }
}

extern "C" void kernel_launch(void* const* d_in, const int* in_sizes, int n_in,
                              void* d_out, int out_size, void* d_ws, size_t ws_size,
                              hipStream_t stream) {
    const fv4*   tables  = (const fv4*)d_in[0];      // [T, N, 4] f32
    const float* W       = (const float*)d_in[1];    // [1, 4]   f32
    const float* bias    = (const float*)d_in[2];    // [1]      f32
    const int*   indices = (const int*)d_in[3];      // [T, TOTAL]
    const int*   segids  = (const int*)d_in[4];      // [T, TOTAL] sorted per table
    float*       out     = (float*)d_out;            // [T*B] f32

    float* p = (float*)d_ws;                         // 16 MB scratch

    {
        // 4 tables x 3908 pinned blocks = 15,632 blocks (covers T*B init too)
        produce_kernel<<<T * BLOCKS_PER_TABLE, 256, 0, stream>>>(tables, W, bias, p, out);
    }
    {
        // T*TOTAL = 3,276,800 threads = 12,800 blocks (multiple of 8 for pinning)
        pool_kernel<<<12800, 256, 0, stream>>>(p, indices, segids, out);
    }
}

// Round 9
// 136.043 us; speedup vs baseline: 1.0405x; 1.0405x over previous
//
#include <hip/hip_runtime.h>

// Problem constants (match reference)
constexpr int T     = 4;
constexpr int NROWS = 1000000;
constexpr int B     = 16384;
constexpr int TOTAL = 16384 * 50; // 819200 lookups per table

// Native clang vector type — required by __builtin_nontemporal_load
typedef float fv4 __attribute__((ext_vector_type(4)));

// ws layout: p[T*NROWS] floats (16 MB, 4 MB per table slice).
//
// XCD-pinning contract (both kernels use the identical mapping):
//   xcd = blockIdx.x & 7 ; table t = xcd >> 1 ; table t's p slice is WRITTEN
//   by and GATHERED by only XCDs {2t, 2t+1}, so the 4 MB slice stays
//   dirty-resident in that pair's L2 between the kernels.
//
// NOTE (R6/7/8 ablation): do NOT use nontemporal loads on the table stream —
// the harness's d_in restore leaves tables L3-warm; nt's no-allocate path
// refetches from HBM and cost +6 us in both R7 and R8. nt is kept ONLY on
// the pool's one-shot idx/seg stream to protect the L2-resident p slice.

constexpr int BLOCKS_PER_TABLE = 3908;  // even; 3908*256 >= NROWS

// Producer: p[t*NROWS + r] = dot(table[t][r], W), regular (L3-warm) loads.
// Fused out[:] = bias init (pool's atomics accumulate on top of bias).
__global__ __launch_bounds__(256)
void produce_kernel(const fv4*   __restrict__ tables,
                    const float* __restrict__ Wp,
                    const float* __restrict__ bias,
                    float* __restrict__ p,
                    float* __restrict__ out) {
    const int xcd    = blockIdx.x & 7;
    const int t      = xcd >> 1;
    const int within = (blockIdx.x >> 3) * 2 + (xcd & 1);   // [0, 3908)
    const int r      = within * 256 + threadIdx.x;

    if (r < NROWS) {
        const float wx = Wp[0], wy = Wp[1], wz = Wp[2], ww = Wp[3];
        const fv4 row = tables[t * NROWS + r];               // regular: L3-warm
        p[t * NROWS + r] = row.x * wx + row.y * wy + row.z * wz + row.w * ww;
    }

    const int gid = blockIdx.x * 256 + threadIdx.x;
    if (gid < T * B) out[gid] = bias[0];
}

// Pool (identical to round-6 best): one lookup per thread, wave-level
// segmented inclusive scan over sorted segment ids (conditional
// Hillis-Steele — valid because equal segs are contiguous); only the last
// lane of each run flushes via atomicAdd (~102k atomics over 65k addresses
// => ~2/address, no serialization).
__global__ __launch_bounds__(256)
void pool_kernel(const float* __restrict__ p,        // [T*NROWS]
                 const int*   __restrict__ indices,  // [T*TOTAL]
                 const int*   __restrict__ segids,   // [T*TOTAL] sorted per table
                 float*       __restrict__ out)      // [T*B], pre-set to bias
{
    // 12800 blocks: 3200 per table (256 lookups each), same XCD mapping as produce.
    const int xcd    = blockIdx.x & 7;
    const int t      = xcd >> 1;
    const int within = (blockIdx.x >> 3) * 2 + (xcd & 1);   // [0, 3200)
    const int local  = within * 256 + threadIdx.x;
    const int g      = t * TOTAL + local;

    const int lane = threadIdx.x & 63;

    const int seg = __builtin_nontemporal_load(&segids[g]);
    const int idx = __builtin_nontemporal_load(&indices[g]);
    float v = p[t * NROWS + idx];

    // Segmented inclusive scan across the 64-lane wave.
    #pragma unroll
    for (int d = 1; d < 64; d <<= 1) {
        const float ov = __shfl_up(v, d, 64);
        const int   os = __shfl_up(seg, d, 64);
        if (lane >= d && os == seg) v += ov;
    }

    // Last lane of each same-seg run in this wave flushes the run sum.
    const int nseg = __shfl_down(seg, 1, 64);
    if (lane == 63 || nseg != seg) {
        atomicAdd(&out[t * B + seg], v);
    }
}

extern "C" void kernel_launch(void* const* d_in, const int* in_sizes, int n_in,
                              void* d_out, int out_size, void* d_ws, size_t ws_size,
                              hipStream_t stream) {
    const fv4*   tables  = (const fv4*)d_in[0];      // [T, N, 4] f32
    const float* W       = (const float*)d_in[1];    // [1, 4]   f32
    const float* bias    = (const float*)d_in[2];    // [1]      f32
    const int*   indices = (const int*)d_in[3];      // [T, TOTAL]
    const int*   segids  = (const int*)d_in[4];      // [T, TOTAL] sorted per table
    float*       out     = (float*)d_out;            // [T*B] f32

    float* p = (float*)d_ws;                         // 16 MB scratch

    {
        // 4 tables x 3908 pinned blocks = 15,632 blocks (covers T*B init too)
        produce_kernel<<<T * BLOCKS_PER_TABLE, 256, 0, stream>>>(tables, W, bias, p, out);
    }
    {
        // T*TOTAL = 3,276,800 threads = 12,800 blocks (multiple of 8 for pinning)
        pool_kernel<<<12800, 256, 0, stream>>>(p, indices, segids, out);
    }
}